// Round 3
// baseline (2613.255 us; speedup 1.0000x reference)
//
#include <hip/hip_runtime.h>
#include <hip/hip_bf16.h>

typedef __hip_bfloat16 bf16;

#define BB 4
#define CC 128
#define HH 128
#define WW 128
#define ND 81
#define PADR 4
#define LT 24            // 16 + 2*4
#define HW (HH*WW)
#define CHW (CC*HW)

__device__ __forceinline__ float b2f(bf16 v){ return __bfloat162float(v); }

// dtype-polymorphic load/store: FP32=1 -> float*, FP32=0 -> bf16*
template<int FP32>
__device__ __forceinline__ float ldf(const void* p, size_t i){
  if (FP32) return ((const float*)p)[i];
  return b2f(((const bf16*)p)[i]);
}
template<int FP32>
__device__ __forceinline__ void stf(void* p, size_t i, float v){
  if (FP32) ((float*)p)[i] = v;
  else      ((bf16*)p)[i] = __float2bfloat16(v);
}

// ---------------------------------------------------------------------------
// detect: interpret filter_map as u16[]; count bf16 NaN/Inf bit patterns.
// True-bf16 N(0,1) data -> 0 hits. fp32 N(0,1) data -> ~128 hits in 65536.
// flag: 1 = inputs are fp32, 0 = inputs are bf16.
// ---------------------------------------------------------------------------
__global__ void detect_kernel(const void* fm, int* flag){
  __shared__ int cnt;
  if (threadIdx.x == 0) cnt = 0;
  __syncthreads();
  const unsigned short* u = (const unsigned short*)fm;
  int local = 0;
  for (int i = threadIdx.x; i < 65536; i += 256)
    if ((u[i] & 0x7F80u) == 0x7F80u) local++;
  atomicAdd(&cnt, local);
  __syncthreads();
  if (threadIdx.x == 0) *flag = (cnt > 0) ? 1 : 0;
}

// ---------------------------------------------------------------------------
// K0: per-displacement coefficients from the 10-bin distance map + 1x1 convs
// coef layout (floats): [0..80]=target, [128..208]=vplus, [256..336]=alo,
//                       [384..464]=ahi, [512]=step_length, [513]=reg_weight
// ---------------------------------------------------------------------------
template<int FP32>
__global__ void coef_kernel(const void* lw, const void* sw, const void* mw,
                            const void* lsl, const void* fr,
                            const int* flag, float* coef){
  if (*flag != FP32) return;
  int d = threadIdx.x;
  if (d < ND){
    float dy = (float)(d / 9) - 4.0f;
    float dx = (float)(d % 9) - 4.0f;
    float dist = sqrtf(dy*dy + dx*dx) * 2.0f;   // / BIN_DISP(0.5)
    float t = 0.f, v = 0.f, m = 0.f;
    for (int k = 0; k < 10; k++){
      float bd = dist - (float)k;
      float val = (k == 9) ? fminf(fmaxf(bd + 1.0f, 0.f), 1.f)
                           : fmaxf(1.0f - fabsf(bd), 0.f);
      t += val * ldf<FP32>(lw, k);
      v += val * ldf<FP32>(sw, k);
      m += val * ldf<FP32>(mw, k);
    }
    float wm = 1.f / (1.f + expf(-m));
    coef[d]       = t;
    coef[128 + d] = v;
    coef[256 + d] = (1.f - wm) * 0.5f;
    coef[384 + d] = (1.f + wm) * 0.5f;
  }
  if (threadIdx.x == 0){
    coef[512] = expf(ldf<FP32>(lsl, 0));
    float f = ldf<FP32>(fr, 0);
    coef[513] = fmaxf(f*f, 1e-10f) / (float)(CC*CC);  // /(c*c)
  }
}

// stage one channel's 24x24 zero-padded ref tile into LDS (fp32)
template<int FP32>
__device__ __forceinline__ void stage_tile(float* tile, const void* ref,
                                           int bb, int ch, int ty0, int tx0){
  for (int e = threadIdx.x; e < LT*LT; e += 256){
    int ly = e / LT, lx = e % LT;
    int gy = ty0 - PADR + ly, gx = tx0 - PADR + lx;
    float v = 0.f;
    if (gy >= 0 && gy < HH && gx >= 0 && gx < WW)
      v = ldf<FP32>(ref, ((size_t)(bb*CC + ch)*HH + gy)*WW + gx);
    tile[e] = v;
  }
}

// ---------------------------------------------------------------------------
// kA: scores (registers only) -> mapped -> f_grad = rw*f + corr_t(mapped)
//     emits bf16 f_grad and packed sign masks of the scores
// ---------------------------------------------------------------------------
template<int FP32>
__global__ __launch_bounds__(256)
void kA(const void* f_in, const void* ref, const float* coef,
        const int* flag, bf16* fgrad, unsigned int* signs){
  if (*flag != FP32) return;
  __shared__ float tile[LT*LT];
  __shared__ float s_t[ND], s_v[ND], s_al[ND], s_ah[ND];
  if (threadIdx.x < ND){
    s_t [threadIdx.x] = coef[      threadIdx.x];
    s_v [threadIdx.x] = coef[128 + threadIdx.x];
    s_al[threadIdx.x] = coef[256 + threadIdx.x];
    s_ah[threadIdx.x] = coef[384 + threadIdx.x];
  }
  int bb  = blockIdx.y;
  int t   = blockIdx.x;
  int ty0 = (t >> 3) << 4;
  int tx0 = (t & 7)  << 4;
  int tx = threadIdx.x & 15, ty = threadIdx.x >> 4;
  int y = ty0 + ty, x = tx0 + tx;

  float acc[ND];
  #pragma unroll
  for (int d = 0; d < ND; d++) acc[d] = 0.f;

  // phase 1: scores = corr(f)
  size_t fbase = ((size_t)(bb*CC)*HH + y)*WW + x;
  for (int ch = 0; ch < CC; ch++){
    stage_tile<FP32>(tile, ref, bb, ch, ty0, tx0);
    __syncthreads();
    float fv = ldf<FP32>(f_in, fbase + (size_t)ch * HW);
    #pragma unroll
    for (int di = 0; di < 9; di++)
      #pragma unroll
      for (int dj = 0; dj < 9; dj++)
        acc[di*9 + dj] += fv * tile[(ty + di)*LT + tx + dj];
    __syncthreads();
  }

  // phase 2: mapped (in place) + sign masks
  unsigned int pm[3] = {0,0,0}, nm[3] = {0,0,0};
  #pragma unroll
  for (int d = 0; d < ND; d++){
    float s = acc[d];
    float sgn = 0.f;
    if (s > 0.f){ sgn =  1.f; pm[d >> 5] |= (1u << (d & 31)); }
    if (s < 0.f){ sgn = -1.f; nm[d >> 5] |= (1u << (d & 31)); }
    float vp = s_v[d], al = s_al[d], ah = s_ah[d];
    float ga  = vp * (al * sgn + ah);
    float act = vp * (al * fabsf(s) + ah * s);
    acc[d] = ga * (act - vp * s_t[d]);     // mapped
  }
  size_t pix = ((size_t)bb*HH + y)*WW + x;
  #pragma unroll
  for (int w = 0; w < 3; w++){
    signs[pix*6 + w]     = pm[w];
    signs[pix*6 + 3 + w] = nm[w];
  }

  // phase 3: f_grad = rw*f + corr_t(mapped)
  float rw = coef[513];
  for (int ch = 0; ch < CC; ch++){
    stage_tile<FP32>(tile, ref, bb, ch, ty0, tx0);
    __syncthreads();
    size_t fi = fbase + (size_t)ch * HW;
    float o = rw * ldf<FP32>(f_in, fi);
    #pragma unroll
    for (int di = 0; di < 9; di++)
      #pragma unroll
      for (int dj = 0; dj < 9; dj++)
        o += acc[di*9 + dj] * tile[(ty + di)*LT + tx + dj];
    fgrad[fi] = __float2bfloat16(o);
    __syncthreads();
  }
}

// ---------------------------------------------------------------------------
// kB: t = corr(f_grad) (vs ref); den = sum_d (ga*t)^2 ; num = sum_c fg^2
//     alpha = num / max(den + rw*num, 1e-8); f_out = f_in - step*alpha*fg
// ---------------------------------------------------------------------------
template<int FP32>
__global__ __launch_bounds__(256)
void kB(const void* f_in, const void* ref, const bf16* fgrad,
        const unsigned int* signs, const float* coef, const int* flag,
        void* f_out){
  if (*flag != FP32) return;
  __shared__ float tile[LT*LT];
  __shared__ float s_v[ND], s_al[ND], s_ah[ND];
  if (threadIdx.x < ND){
    s_v [threadIdx.x] = coef[128 + threadIdx.x];
    s_al[threadIdx.x] = coef[256 + threadIdx.x];
    s_ah[threadIdx.x] = coef[384 + threadIdx.x];
  }
  int bb  = blockIdx.y;
  int t   = blockIdx.x;
  int ty0 = (t >> 3) << 4;
  int tx0 = (t & 7)  << 4;
  int tx = threadIdx.x & 15, ty = threadIdx.x >> 4;
  int y = ty0 + ty, x = tx0 + tx;

  float acc[ND];
  #pragma unroll
  for (int d = 0; d < ND; d++) acc[d] = 0.f;
  float num = 0.f;

  size_t fbase = ((size_t)(bb*CC)*HH + y)*WW + x;
  for (int ch = 0; ch < CC; ch++){
    stage_tile<FP32>(tile, ref, bb, ch, ty0, tx0);
    __syncthreads();
    float gv = b2f(fgrad[fbase + (size_t)ch * HW]);
    num += gv * gv;
    #pragma unroll
    for (int di = 0; di < 9; di++)
      #pragma unroll
      for (int dj = 0; dj < 9; dj++)
        acc[di*9 + dj] += gv * tile[(ty + di)*LT + tx + dj];
    __syncthreads();
  }

  // reconstruct grad_act from sign masks, reduce den
  size_t pix = ((size_t)bb*HH + y)*WW + x;
  unsigned int pm[3], nm[3];
  #pragma unroll
  for (int w = 0; w < 3; w++){
    pm[w] = signs[pix*6 + w];
    nm[w] = signs[pix*6 + 3 + w];
  }
  float den = 0.f;
  #pragma unroll
  for (int d = 0; d < ND; d++){
    float sgn = ((pm[d >> 5] >> (d & 31)) & 1u) ? 1.f
              : (((nm[d >> 5] >> (d & 31)) & 1u) ? -1.f : 0.f);
    float ga = s_v[d] * (s_al[d] * sgn + s_ah[d]);
    float sg = ga * acc[d];
    den += sg * sg;
  }
  float rw   = coef[513];
  float step = coef[512];
  float alpha = num / fmaxf(den + rw * num, 1e-8f);
  float sa = step * alpha;

  // update: f_out = f_in - step*alpha*f_grad  (own pixel, all channels)
  for (int ch = 0; ch < CC; ch++){
    size_t fi = fbase + (size_t)ch * HW;
    float v = ldf<FP32>(f_in, fi) - sa * b2f(fgrad[fi]);
    stf<FP32>(f_out, fi, v);
  }
}

// ---------------------------------------------------------------------------
extern "C" void kernel_launch(void* const* d_in, const int* in_sizes, int n_in,
                              void* d_out, int out_size, void* d_ws, size_t ws_size,
                              hipStream_t stream) {
  const void* filter_map = d_in[0];
  const void* ref        = d_in[1];
  const void* label_w    = d_in[2];
  const void* spatial_w  = d_in[3];
  const void* mask_w     = d_in[4];
  const void* lsl        = d_in[5];
  const void* freg       = d_in[6];

  // ws layout (~17.5 MB total):
  //   coef  : floats [0..513] used; flag int at byte 3072
  //   fgrad : BB*CHW bf16   (16.78 MB)
  //   signs : BB*HW*6 u32   (1.57 MB)
  char*  wsb   = (char*)d_ws;
  float* coef  = (float*)wsb;
  int*   flag  = (int*)(wsb + 3072);
  bf16*  fgrad = (bf16*)(wsb + 4096);
  unsigned int* signs = (unsigned int*)(wsb + 4096 + (size_t)BB*CHW*sizeof(bf16));
  void*  fbuf  = d_out;   // current filter lives in d_out (dtype per flag)

  detect_kernel<<<dim3(1), dim3(256), 0, stream>>>(filter_map, flag);
  coef_kernel<0><<<dim3(1), dim3(128), 0, stream>>>(label_w, spatial_w, mask_w, lsl, freg, flag, coef);
  coef_kernel<1><<<dim3(1), dim3(128), 0, stream>>>(label_w, spatial_w, mask_w, lsl, freg, flag, coef);

  dim3 grid(64, BB);   // 8x8 tiles of 16x16 pixels, per batch image
  for (int it = 0; it < 3; it++){
    const void* fsrc = (it == 0) ? filter_map : (const void*)fbuf;
    kA<0><<<grid, 256, 0, stream>>>(fsrc, ref, coef, flag, fgrad, signs);
    kA<1><<<grid, 256, 0, stream>>>(fsrc, ref, coef, flag, fgrad, signs);
    kB<0><<<grid, 256, 0, stream>>>(fsrc, ref, fgrad, signs, coef, flag, fbuf);
    kB<1><<<grid, 256, 0, stream>>>(fsrc, ref, fgrad, signs, coef, flag, fbuf);
  }
}

// Round 4
// 2367.457 us; speedup vs baseline: 1.1038x; 1.1038x over previous
//
#include <hip/hip_runtime.h>
#include <hip/hip_bf16.h>

typedef __hip_bfloat16 bf16;

#define BB 4
#define CC 128
#define HH 128
#define WW 128
#define ND 81
#define PADR 4
#define LT 24            // 16 + 2*4
#define TILE_ELEMS (LT*LT)   // 576
#define HW (HH*WW)
#define CHW (CC*HW)
#define NQ 4             // channel quarters
#define QC (CC/NQ)       // 32 channels per quarter
#define NR 16            // staging rounds per phase (2 ch per quarter per round)

__device__ __forceinline__ float b2f(bf16 v){ return __bfloat162float(v); }

// dtype-polymorphic load/store: FP32=1 -> float*, FP32=0 -> bf16*
template<int FP32>
__device__ __forceinline__ float ldf(const void* p, size_t i){
  if (FP32) return ((const float*)p)[i];
  return b2f(((const bf16*)p)[i]);
}
template<int FP32>
__device__ __forceinline__ void stf(void* p, size_t i, float v){
  if (FP32) ((float*)p)[i] = v;
  else      ((bf16*)p)[i] = __float2bfloat16(v);
}

// ---------------------------------------------------------------------------
// detect: count bf16 NaN/Inf bit patterns in filter_map's first 64K u16s.
// bf16 N(0,1) data -> 0 hits; fp32 data -> ~128 hits. flag: 1=fp32, 0=bf16.
// ---------------------------------------------------------------------------
__global__ void detect_kernel(const void* fm, int* flag){
  __shared__ int cnt;
  if (threadIdx.x == 0) cnt = 0;
  __syncthreads();
  const unsigned short* u = (const unsigned short*)fm;
  int local = 0;
  for (int i = threadIdx.x; i < 65536; i += 256)
    if ((u[i] & 0x7F80u) == 0x7F80u) local++;
  atomicAdd(&cnt, local);
  __syncthreads();
  if (threadIdx.x == 0) *flag = (cnt > 0) ? 1 : 0;
}

// ---------------------------------------------------------------------------
// coef: [0..80]=target, [128..208]=vplus, [256..336]=alo, [384..464]=ahi,
//       [512]=step_length, [513]=reg_weight
// ---------------------------------------------------------------------------
template<int FP32>
__global__ void coef_kernel(const void* lw, const void* sw, const void* mw,
                            const void* lsl, const void* fr,
                            const int* flag, float* coef){
  if (*flag != FP32) return;
  int d = threadIdx.x;
  if (d < ND){
    float dy = (float)(d / 9) - 4.0f;
    float dx = (float)(d % 9) - 4.0f;
    float dist = sqrtf(dy*dy + dx*dx) * 2.0f;
    float t = 0.f, v = 0.f, m = 0.f;
    for (int k = 0; k < 10; k++){
      float bd = dist - (float)k;
      float val = (k == 9) ? fminf(fmaxf(bd + 1.0f, 0.f), 1.f)
                           : fmaxf(1.0f - fabsf(bd), 0.f);
      t += val * ldf<FP32>(lw, k);
      v += val * ldf<FP32>(sw, k);
      m += val * ldf<FP32>(mw, k);
    }
    float wm = 1.f / (1.f + expf(-m));
    coef[d]       = t;
    coef[128 + d] = v;
    coef[256 + d] = (1.f - wm) * 0.5f;
    coef[384 + d] = (1.f + wm) * 0.5f;
  }
  if (threadIdx.x == 0){
    coef[512] = expf(ldf<FP32>(lsl, 0));
    float f = ldf<FP32>(fr, 0);
    coef[513] = fmaxf(f*f, 1e-10f) / (float)(CC*CC);
  }
}

// ---------------------------------------------------------------------------
// kA: phase1 corr(f) (channel-split over 4 quarters) -> LDS all-reduce ->
//     phase2 mapped + signs -> phase3 f_grad = rw*f + corr_t(mapped)
// block: 1024 thr = 4 quarters x 256 pixels (16x16 tile). grid: (64, BB).
// ---------------------------------------------------------------------------
template<int FP32>
__global__ __launch_bounds__(1024, 4)
void kA(const void* f_in, const void* ref, const float* coef,
        const int* flag, bf16* fgrad, unsigned int* signs){
  if (*flag != FP32) return;
  __shared__ float tileF[8*TILE_ELEMS];          // 8 channel tiles, 18.4 KB
  __shared__ float red[9*NQ*256];                // all-reduce buffer, 36 KB
  __shared__ float s_t[ND], s_v[ND], s_al[ND], s_ah[ND];

  int tid = threadIdx.x;
  int q   = tid >> 8;          // channel quarter 0..3
  int p   = tid & 255;         // pixel index within 16x16 tile
  int tx  = p & 15, ty = p >> 4;
  int bb  = blockIdx.y;
  int t   = blockIdx.x;
  int ty0 = (t >> 3) << 4;
  int tx0 = (t & 7)  << 4;
  int y = ty0 + ty, x = tx0 + tx;

  if (tid < ND){
    s_t [tid] = coef[      tid];
    s_v [tid] = coef[128 + tid];
    s_al[tid] = coef[256 + tid];
    s_ah[tid] = coef[384 + tid];
  }

  size_t ibase = ((size_t)(bb*CC)*HH + y)*WW + x;   // + c*HW per channel

  auto stage8 = [&](int r){
    // slot s in 0..7 holds channel ((s>>1)*QC + r*2 + (s&1))
    for (int e = tid; e < 8*TILE_ELEMS; e += 1024){
      int s   = e / TILE_ELEMS;
      int idx = e - s*TILE_ELEMS;
      int ly  = idx / LT, lx = idx - ly*LT;
      int ch  = ((s >> 1) * QC) + (r << 1) + (s & 1);
      int gy  = ty0 - PADR + ly, gx = tx0 - PADR + lx;
      float v = 0.f;
      if (gy >= 0 && gy < HH && gx >= 0 && gx < WW)
        v = ldf<FP32>(ref, ((size_t)(bb*CC + ch)*HH + gy)*WW + gx);
      tileF[e] = v;
    }
  };

  float acc[ND];
  #pragma unroll
  for (int d = 0; d < ND; d++) acc[d] = 0.f;

  // ---- phase 1: partial corr over this quarter's 32 channels ----
  for (int r = 0; r < NR; r++){
    __syncthreads();
    stage8(r);
    __syncthreads();
    int ch0 = q*QC + (r << 1);
    #pragma unroll
    for (int s = 0; s < 2; s++){
      float fv = ldf<FP32>(f_in, ibase + (size_t)(ch0 + s) * HW);
      const float* tl = &tileF[(q*2 + s) * TILE_ELEMS];
      #pragma unroll
      for (int di = 0; di < 9; di++)
        #pragma unroll
        for (int dj = 0; dj < 9; dj++)
          acc[di*9 + dj] += fv * tl[(ty + di)*LT + tx + dj];
    }
  }

  // ---- all-reduce acc over quarters (9 chunks of 9) ----
  #pragma unroll
  for (int c0 = 0; c0 < 81; c0 += 9){
    __syncthreads();
    #pragma unroll
    for (int j = 0; j < 9; j++) red[(j*NQ + q)*256 + p] = acc[c0 + j];
    __syncthreads();
    #pragma unroll
    for (int j = 0; j < 9; j++)
      acc[c0 + j] = red[(j*NQ + 0)*256 + p] + red[(j*NQ + 1)*256 + p]
                  + red[(j*NQ + 2)*256 + p] + red[(j*NQ + 3)*256 + p];
  }

  // ---- phase 2: mapped (in place) + sign masks (quarter 0 writes) ----
  unsigned int pm[3] = {0,0,0}, nm[3] = {0,0,0};
  #pragma unroll
  for (int d = 0; d < ND; d++){
    float s = acc[d];
    float sgn = 0.f;
    if (s > 0.f){ sgn =  1.f; pm[d >> 5] |= (1u << (d & 31)); }
    if (s < 0.f){ sgn = -1.f; nm[d >> 5] |= (1u << (d & 31)); }
    float vp = s_v[d], al = s_al[d], ah = s_ah[d];
    float ga  = vp * (al * sgn + ah);
    float act = vp * (al * fabsf(s) + ah * s);
    acc[d] = ga * (act - vp * s_t[d]);     // mapped
  }
  if (q == 0){
    size_t pix = (size_t)bb*HW + (size_t)y*WW + x;
    #pragma unroll
    for (int w = 0; w < 3; w++){
      signs[pix*6 + w]     = pm[w];
      signs[pix*6 + 3 + w] = nm[w];
    }
  }

  // ---- phase 3: f_grad = rw*f + corr_t(mapped), quarter's channels ----
  float rw = coef[513];
  for (int r = 0; r < NR; r++){
    __syncthreads();
    stage8(r);
    __syncthreads();
    int ch0 = q*QC + (r << 1);
    #pragma unroll
    for (int s = 0; s < 2; s++){
      size_t fi = ibase + (size_t)(ch0 + s) * HW;
      float o = rw * ldf<FP32>(f_in, fi);
      const float* tl = &tileF[(q*2 + s) * TILE_ELEMS];
      #pragma unroll
      for (int di = 0; di < 9; di++)
        #pragma unroll
        for (int dj = 0; dj < 9; dj++)
          o += acc[di*9 + dj] * tl[(ty + di)*LT + tx + dj];
      fgrad[fi] = __float2bfloat16(o);
    }
  }
}

// ---------------------------------------------------------------------------
// kB: phase1 corr(fgrad)+num (channel-split) -> all-reduce (81 + num) ->
//     phase2 den/alpha from signs -> phase3 f_out = f_in - step*alpha*fgrad
// ---------------------------------------------------------------------------
template<int FP32>
__global__ __launch_bounds__(1024, 4)
void kB(const void* f_in, const void* ref, const bf16* fgrad,
        const unsigned int* signs, const float* coef, const int* flag,
        void* f_out){
  if (*flag != FP32) return;
  __shared__ float tileF[8*TILE_ELEMS];
  __shared__ float red[9*NQ*256];
  __shared__ float s_v[ND], s_al[ND], s_ah[ND];

  int tid = threadIdx.x;
  int q   = tid >> 8;
  int p   = tid & 255;
  int tx  = p & 15, ty = p >> 4;
  int bb  = blockIdx.y;
  int t   = blockIdx.x;
  int ty0 = (t >> 3) << 4;
  int tx0 = (t & 7)  << 4;
  int y = ty0 + ty, x = tx0 + tx;

  if (tid < ND){
    s_v [tid] = coef[128 + tid];
    s_al[tid] = coef[256 + tid];
    s_ah[tid] = coef[384 + tid];
  }

  size_t ibase = ((size_t)(bb*CC)*HH + y)*WW + x;

  auto stage8 = [&](int r){
    for (int e = tid; e < 8*TILE_ELEMS; e += 1024){
      int s   = e / TILE_ELEMS;
      int idx = e - s*TILE_ELEMS;
      int ly  = idx / LT, lx = idx - ly*LT;
      int ch  = ((s >> 1) * QC) + (r << 1) + (s & 1);
      int gy  = ty0 - PADR + ly, gx = tx0 - PADR + lx;
      float v = 0.f;
      if (gy >= 0 && gy < HH && gx >= 0 && gx < WW)
        v = ldf<FP32>(ref, ((size_t)(bb*CC + ch)*HH + gy)*WW + gx);
      tileF[e] = v;
    }
  };

  float acc[ND];
  #pragma unroll
  for (int d = 0; d < ND; d++) acc[d] = 0.f;
  float num = 0.f;

  // ---- phase 1: partial corr(fgrad) + partial num ----
  for (int r = 0; r < NR; r++){
    __syncthreads();
    stage8(r);
    __syncthreads();
    int ch0 = q*QC + (r << 1);
    #pragma unroll
    for (int s = 0; s < 2; s++){
      float gv = b2f(fgrad[ibase + (size_t)(ch0 + s) * HW]);
      num += gv * gv;
      const float* tl = &tileF[(q*2 + s) * TILE_ELEMS];
      #pragma unroll
      for (int di = 0; di < 9; di++)
        #pragma unroll
        for (int dj = 0; dj < 9; dj++)
          acc[di*9 + dj] += gv * tl[(ty + di)*LT + tx + dj];
    }
  }

  // ---- all-reduce acc (81) + num over quarters ----
  #pragma unroll
  for (int c0 = 0; c0 < 81; c0 += 9){
    __syncthreads();
    #pragma unroll
    for (int j = 0; j < 9; j++) red[(j*NQ + q)*256 + p] = acc[c0 + j];
    __syncthreads();
    #pragma unroll
    for (int j = 0; j < 9; j++)
      acc[c0 + j] = red[(j*NQ + 0)*256 + p] + red[(j*NQ + 1)*256 + p]
                  + red[(j*NQ + 2)*256 + p] + red[(j*NQ + 3)*256 + p];
  }
  __syncthreads();
  red[q*256 + p] = num;
  __syncthreads();
  num = red[0*256 + p] + red[1*256 + p] + red[2*256 + p] + red[3*256 + p];

  // ---- phase 2: den from signs, alpha ----
  size_t pix = (size_t)bb*HW + (size_t)y*WW + x;
  unsigned int pm[3], nm[3];
  #pragma unroll
  for (int w = 0; w < 3; w++){
    pm[w] = signs[pix*6 + w];
    nm[w] = signs[pix*6 + 3 + w];
  }
  float den = 0.f;
  #pragma unroll
  for (int d = 0; d < ND; d++){
    float sgn = ((pm[d >> 5] >> (d & 31)) & 1u) ? 1.f
              : (((nm[d >> 5] >> (d & 31)) & 1u) ? -1.f : 0.f);
    float ga = s_v[d] * (s_al[d] * sgn + s_ah[d]);
    float sg = ga * acc[d];
    den += sg * sg;
  }
  float rw   = coef[513];
  float step = coef[512];
  float alpha = num / fmaxf(den + rw * num, 1e-8f);
  float sa = step * alpha;

  // ---- phase 3: update this quarter's channels ----
  for (int c = 0; c < QC; c++){
    size_t fi = ibase + (size_t)(q*QC + c) * HW;
    float v = ldf<FP32>(f_in, fi) - sa * b2f(fgrad[fi]);
    stf<FP32>(f_out, fi, v);
  }
}

// ---------------------------------------------------------------------------
extern "C" void kernel_launch(void* const* d_in, const int* in_sizes, int n_in,
                              void* d_out, int out_size, void* d_ws, size_t ws_size,
                              hipStream_t stream) {
  const void* filter_map = d_in[0];
  const void* ref        = d_in[1];
  const void* label_w    = d_in[2];
  const void* spatial_w  = d_in[3];
  const void* mask_w     = d_in[4];
  const void* lsl        = d_in[5];
  const void* freg       = d_in[6];

  // ws layout (~17.5 MB): coef floats [0..513]; flag int at byte 3072;
  // fgrad BB*CHW bf16 (16.78 MB); signs BB*HW*6 u32 (1.57 MB)
  char*  wsb   = (char*)d_ws;
  float* coef  = (float*)wsb;
  int*   flag  = (int*)(wsb + 3072);
  bf16*  fgrad = (bf16*)(wsb + 4096);
  unsigned int* signs = (unsigned int*)(wsb + 4096 + (size_t)BB*CHW*sizeof(bf16));
  void*  fbuf  = d_out;   // current filter lives in d_out (dtype per flag)

  detect_kernel<<<dim3(1), dim3(256), 0, stream>>>(filter_map, flag);
  coef_kernel<0><<<dim3(1), dim3(128), 0, stream>>>(label_w, spatial_w, mask_w, lsl, freg, flag, coef);
  coef_kernel<1><<<dim3(1), dim3(128), 0, stream>>>(label_w, spatial_w, mask_w, lsl, freg, flag, coef);

  dim3 grid(64, BB);   // 8x8 tiles of 16x16 pixels, per batch image
  for (int it = 0; it < 3; it++){
    const void* fsrc = (it == 0) ? filter_map : (const void*)fbuf;
    kA<0><<<grid, 1024, 0, stream>>>(fsrc, ref, coef, flag, fgrad, signs);
    kA<1><<<grid, 1024, 0, stream>>>(fsrc, ref, coef, flag, fgrad, signs);
    kB<0><<<grid, 1024, 0, stream>>>(fsrc, ref, fgrad, signs, coef, flag, fbuf);
    kB<1><<<grid, 1024, 0, stream>>>(fsrc, ref, fgrad, signs, coef, flag, fbuf);
  }
}

// Round 5
// 1025.322 us; speedup vs baseline: 2.5487x; 2.3090x over previous
//
#include <hip/hip_runtime.h>

#define BB 4
#define CC 128
#define HH 128
#define WW 128
#define HW (HH*WW)
#define CHW (CC*HW)
#define ND 81
#define CP 136      // padded channel stride (shorts) for [y][x][c] LDS layouts (136*2B = 272 ≡ 0 mod 16, bank-spread)
#define UPITCH 40   // padded u stride (shorts) for [c][u] layout (80 B, 16B-aligned rows, 2-way banks)
#define PP 32       // P tile u stride (shorts)

typedef short s8 __attribute__((ext_vector_type(8)));   // 8 bf16 (4 VGPRs) MFMA A/B frag
typedef float f4 __attribute__((ext_vector_type(4)));   // MFMA C/D frag

__device__ __forceinline__ short f2bf(float x){          // RNE float->bf16 bits
  unsigned u = __float_as_uint(x);
  unsigned r = (u + 0x7FFFu + ((u >> 16) & 1u)) >> 16;
  return (short)r;
}
__device__ __forceinline__ float bf2f(short s){
  return __uint_as_float(((unsigned)(unsigned short)s) << 16);
}

// ---------------------------------------------------------------------------
// coef: [0..80]=target, [128..208]=vplus, [256..336]=alo, [384..464]=ahi,
//       [512]=step_length, [513]=reg_weight   (inputs are fp32 — confirmed r3/r4)
// ---------------------------------------------------------------------------
__global__ void coef_kernel(const float* lw, const float* sw, const float* mw,
                            const float* lsl, const float* fr, float* coef){
  int d = threadIdx.x;
  if (d < ND){
    float dy = (float)(d / 9) - 4.0f;
    float dx = (float)(d % 9) - 4.0f;
    float dist = sqrtf(dy*dy + dx*dx) * 2.0f;
    float t = 0.f, v = 0.f, m = 0.f;
    for (int k = 0; k < 10; k++){
      float bd = dist - (float)k;
      float val = (k == 9) ? fminf(fmaxf(bd + 1.0f, 0.f), 1.f)
                           : fmaxf(1.0f - fabsf(bd), 0.f);
      t += val * lw[k]; v += val * sw[k]; m += val * mw[k];
    }
    float wm = 1.f / (1.f + expf(-m));
    coef[d] = t; coef[128+d] = v;
    coef[256+d] = (1.f - wm) * 0.5f;
    coef[384+d] = (1.f + wm) * 0.5f;
  }
  if (threadIdx.x == 0){
    coef[512] = expf(lsl[0]);
    float f = fr[0];
    coef[513] = fmaxf(f*f, 1e-10f) / (float)(CC*CC);
  }
}

// ---------------------------------------------------------------------------
// kA: per block (bb, 4-row y-band, 16-col x-tile):
//   slide over 12 ref rows r; wave w owns output row y=w; dy = rr - w.
//   corr1 (MFMA, M=x N=u K=c, f hi/lo split) -> scores C[x,u] ->
//   mapped + sign bits -> P[x,u] (bf16, banded) ->
//   corr_t (MFMA, M=x N=c K=u): fgrad frags accumulate over dy.
// LDS (59.5 KB): f_hi 17408 | f_lo 17408 | uc 8704 | cu 10240 | P 4096 |
//                coefs 1536 | signs 1536   (fgs epilogue overlays uc+cu)
// ---------------------------------------------------------------------------
#define KA_F_HI 0
#define KA_F_LO 17408
#define KA_UC   34816
#define KA_CU   43520
#define KA_P    53760
#define KA_CF   57856
#define KA_SG   59392
#define KA_SZ   60928
#define KA_FGS  34816   // 16384 B overlay (uc+cu region) for coalesced fgrad write

__global__ __launch_bounds__(256)
void kA(const float* f_in, const float* ref, const float* coef,
        short* fgrad, unsigned* signs){
  __shared__ char smem[KA_SZ];
  short* f_hi = (short*)(smem + KA_F_HI);
  short* f_lo = (short*)(smem + KA_F_LO);
  short* uc   = (short*)(smem + KA_UC);   // [32 u][CP c]  (c contiguous)
  short* cu   = (short*)(smem + KA_CU);   // [128 c][UPITCH u]  (u contiguous)
  short* Pm   = (short*)(smem + KA_P);    // [4 wv][16 x][PP u]
  float* s_t  = (float*)(smem + KA_CF);
  float* s_v  = s_t + 96; float* s_al = s_t + 192; float* s_ah = s_t + 288;
  unsigned* sg = (unsigned*)(smem + KA_SG);

  int tid = threadIdx.x;
  int lane = tid & 63, wv = tid >> 6;
  int quad = lane >> 4, col = lane & 15;
  int bb = blockIdx.z, y0 = blockIdx.y * 4, x0 = blockIdx.x * 16;
  int ub = x0 - 8;

  if (tid < ND){
    s_t[tid]  = coef[tid];       s_v[tid]  = coef[128+tid];
    s_al[tid] = coef[256+tid];   s_ah[tid] = coef[384+tid];
  }
  for (int e = tid; e < 384; e += 256) sg[e] = 0;

  // stage f band [4y][16x][c] as hi/lo bf16 split (f effectively exact)
  const float* fimg = f_in + (size_t)bb * CHW;
  for (int e = tid; e < 8192; e += 256){
    int x = e & 15, y = (e >> 4) & 3, c = e >> 6;
    float v = fimg[(size_t)c * HW + (y0 + y) * WW + x0 + x];
    short h = f2bf(v);
    f_hi[(y*16 + x)*CP + c] = h;
    f_lo[(y*16 + x)*CP + c] = f2bf(v - bf2f(h));
  }
  __syncthreads();

  // preload this wave's A-frags (row y = wv), reused across all dy
  s8 a_hi[4], a_lo[4];
  #pragma unroll
  for (int kc = 0; kc < 4; kc++){
    int off = (wv*16 + col)*CP + kc*32 + quad*8;
    a_hi[kc] = *(const s8*)&f_hi[off];
    a_lo[kc] = *(const s8*)&f_lo[off];
  }

  f4 D[8];
  #pragma unroll
  for (int i = 0; i < 8; i++) D[i] = (f4)0.f;   // fgrad accum: 8 c-tiles x 4

  const float* rimg = ref + (size_t)bb * CHW;
  for (int rr = 0; rr < 12; rr++){
    int r = y0 + rr - 4;
    __syncthreads();
    if (r >= 0 && r < HH){
      for (int e = tid; e < 4096; e += 256){
        int u = e & 31, c = e >> 5;          // consecutive lanes -> consecutive u (coalesced)
        int ua = ub + u;
        float v = (ua >= 0 && ua < WW) ? rimg[(size_t)c * HW + r * WW + ua] : 0.f;
        short h = f2bf(v);
        uc[u*CP + c] = h;
        cu[c*UPITCH + u] = h;
      }
    }
    __syncthreads();
    int dy = rr - wv;
    if (r >= 0 && r < HH && dy >= 0 && dy <= 8){
      // ---- corr1: C[x,u] = sum_c (f_hi+f_lo)[x,c] * ref[c,u] ----
      f4 C0 = (f4)0.f, C1 = (f4)0.f;
      #pragma unroll
      for (int kc = 0; kc < 4; kc++){
        s8 b0 = *(const s8*)&uc[col*CP        + kc*32 + quad*8];
        s8 b1 = *(const s8*)&uc[(16+col)*CP   + kc*32 + quad*8];
        C0 = __builtin_amdgcn_mfma_f32_16x16x32_bf16(a_hi[kc], b0, C0, 0,0,0);
        C0 = __builtin_amdgcn_mfma_f32_16x16x32_bf16(a_lo[kc], b0, C0, 0,0,0);
        C1 = __builtin_amdgcn_mfma_f32_16x16x32_bf16(a_hi[kc], b1, C1, 0,0,0);
        C1 = __builtin_amdgcn_mfma_f32_16x16x32_bf16(a_lo[kc], b1, C1, 0,0,0);
      }
      // ---- extract scores -> signs + mapped -> P[x,u] (every entry written once) ----
      #pragma unroll
      for (int nt = 0; nt < 2; nt++){
        f4 Cv = nt ? C1 : C0;
        #pragma unroll
        for (int reg = 0; reg < 4; reg++){
          int x  = quad*4 + reg;            // C/D row = (lane>>4)*4 + reg
          int up = nt*16 + col;             // C/D col = lane&15 (+tile offset)
          int dxm = up - x - 4;             // displacement index 0..8 inside band
          float m = 0.f;
          if (dxm >= 0 && dxm <= 8){
            float s = Cv[reg];
            int d = dy*9 + dxm;
            int px = wv*16 + x;
            float sgn = 0.f;
            if (s > 0.f){ sgn =  1.f; atomicOr(&sg[px*6     + (d>>5)], 1u << (d & 31)); }
            if (s < 0.f){ sgn = -1.f; atomicOr(&sg[px*6 + 3 + (d>>5)], 1u << (d & 31)); }
            float vp = s_v[d], al = s_al[d], ah = s_ah[d];
            float ga  = vp * (al * sgn + ah);
            float act = vp * (al * fabsf(s) + ah * s);
            m = ga * (act - vp * s_t[d]);
          }
          Pm[(wv*16 + x)*PP + up] = f2bf(m);
        }
      }
      __builtin_amdgcn_s_waitcnt(0);        // wave-local: P writes visible to own reads
      // ---- corr_t: D[x,c] += sum_u P[x,u] * ref[u,c] ----
      s8 pa = *(const s8*)&Pm[(wv*16 + col)*PP + quad*8];
      #pragma unroll
      for (int ct = 0; ct < 8; ct++){
        s8 bc = *(const s8*)&cu[(ct*16 + col)*UPITCH + quad*8];
        D[ct] = __builtin_amdgcn_mfma_f32_16x16x32_bf16(pa, bc, D[ct], 0,0,0);
      }
    }
  }

  // ---- epilogue: fgrad = rw*f + D, staged through LDS for coalesced write ----
  float rw = coef[513];
  __syncthreads();
  short* fgs = (short*)(smem + KA_FGS);     // [4y][16x][128c]
  #pragma unroll
  for (int ct = 0; ct < 8; ct++){
    #pragma unroll
    for (int reg = 0; reg < 4; reg++){
      int x = quad*4 + reg;
      int c = ct*16 + col;
      int fo = (wv*16 + x)*CP + c;
      float fv = bf2f(f_hi[fo]) + bf2f(f_lo[fo]);
      fgs[(wv*16 + x)*128 + c] = f2bf(D[ct][reg] + rw * fv);
    }
  }
  __syncthreads();
  short* gimg = fgrad + (size_t)bb * CHW;
  for (int e = tid; e < 8192; e += 256){
    int x = e & 15, y = (e >> 4) & 3, c = e >> 6;
    gimg[(size_t)c * HW + (y0 + y) * WW + x0 + x] = fgs[(y*16 + x)*128 + c];
  }
  if (tid < 64){
    size_t gp = ((size_t)bb * HH + y0 + (tid >> 4)) * WW + x0 + (tid & 15);
    #pragma unroll
    for (int w = 0; w < 6; w++) signs[gp*6 + w] = sg[tid*6 + w];
  }
}

// ---------------------------------------------------------------------------
// kB: t = corr(fgrad) via MFMA; den = sum_d (ga*t)^2 (LDS f32 atomics);
//     num = sum_c fg^2; alpha; f_out = f_in - step*alpha*fgrad.
// LDS ~29 KB -> high residency.
// ---------------------------------------------------------------------------
__global__ __launch_bounds__(256)
void kB(const float* f_in, const float* ref, const short* fgrad,
        const unsigned* signs, const float* coef, float* f_out){
  __shared__ char smem[29952];
  short* fg  = (short*)(smem);              // [4y][16x][CP c]
  short* uc  = (short*)(smem + 17408);      // [32 u][CP c]
  float* s_v = (float*)(smem + 26112); float* s_al = s_v + 96; float* s_ah = s_v + 192;
  unsigned* sg = (unsigned*)(smem + 27648);
  float* den = (float*)(smem + 29184);
  float* num = den + 64;
  float* sa  = den + 128;

  int tid = threadIdx.x, lane = tid & 63, wv = tid >> 6;
  int quad = lane >> 4, col = lane & 15;
  int bb = blockIdx.z, y0 = blockIdx.y*4, x0 = blockIdx.x*16, ub = x0 - 8;

  if (tid < ND){ s_v[tid] = coef[128+tid]; s_al[tid] = coef[256+tid]; s_ah[tid] = coef[384+tid]; }
  if (tid < 64) den[tid] = 0.f;

  const short* gimg = fgrad + (size_t)bb*CHW;
  for (int e = tid; e < 8192; e += 256){
    int x = e & 15, y = (e>>4)&3, c = e>>6;
    fg[(y*16+x)*CP + c] = gimg[(size_t)c*HW + (y0+y)*WW + x0 + x];
  }
  if (tid < 64){
    size_t gp = ((size_t)bb*HH + y0 + (tid>>4))*WW + x0 + (tid&15);
    #pragma unroll
    for (int w = 0; w < 6; w++) sg[tid*6 + w] = signs[gp*6 + w];
  }
  __syncthreads();

  // num per pixel
  if (tid < 64){
    float s = 0.f;
    for (int kc = 0; kc < 16; kc++){
      s8 v = *(const s8*)&fg[tid*CP + kc*8];
      #pragma unroll
      for (int j = 0; j < 8; j++){ float f = bf2f(v[j]); s += f*f; }
    }
    num[tid] = s;
  }

  s8 a[4];
  #pragma unroll
  for (int kc = 0; kc < 4; kc++)
    a[kc] = *(const s8*)&fg[(wv*16+col)*CP + kc*32 + quad*8];

  const float* rimg = ref + (size_t)bb*CHW;
  for (int rr = 0; rr < 12; rr++){
    int r = y0 + rr - 4;
    __syncthreads();
    if (r >= 0 && r < HH){
      for (int e = tid; e < 4096; e += 256){
        int u = e & 31, c = e >> 5;
        int ua = ub + u;
        float v = (ua >= 0 && ua < WW) ? rimg[(size_t)c*HW + r*WW + ua] : 0.f;
        uc[u*CP + c] = f2bf(v);
      }
    }
    __syncthreads();
    int dy = rr - wv;
    if (r >= 0 && r < HH && dy >= 0 && dy <= 8){
      f4 C0 = (f4)0.f, C1 = (f4)0.f;
      #pragma unroll
      for (int kc = 0; kc < 4; kc++){
        s8 b0 = *(const s8*)&uc[col*CP      + kc*32 + quad*8];
        s8 b1 = *(const s8*)&uc[(16+col)*CP + kc*32 + quad*8];
        C0 = __builtin_amdgcn_mfma_f32_16x16x32_bf16(a[kc], b0, C0, 0,0,0);
        C1 = __builtin_amdgcn_mfma_f32_16x16x32_bf16(a[kc], b1, C1, 0,0,0);
      }
      #pragma unroll
      for (int nt = 0; nt < 2; nt++){
        f4 Cv = nt ? C1 : C0;
        #pragma unroll
        for (int reg = 0; reg < 4; reg++){
          int x  = quad*4 + reg;
          int up = nt*16 + col;
          int dxm = up - x - 4;
          if (dxm >= 0 && dxm <= 8){
            int d = dy*9 + dxm;
            int px = wv*16 + x;
            float sgn = ((sg[px*6 + (d>>5)] >> (d&31)) & 1u) ? 1.f
                      : (((sg[px*6 + 3 + (d>>5)] >> (d&31)) & 1u) ? -1.f : 0.f);
            float ga = s_v[d] * (s_al[d]*sgn + s_ah[d]);
            float t  = Cv[reg];
            float sgv = ga * t;
            atomicAdd(&den[px], sgv*sgv);
          }
        }
      }
    }
  }
  __syncthreads();
  if (tid < 64){
    float rw = coef[513], step = coef[512];
    float alpha = num[tid] / fmaxf(den[tid] + rw*num[tid], 1e-8f);
    sa[tid] = step * alpha;
  }
  __syncthreads();
  const float* fimg = f_in + (size_t)bb*CHW;
  float* oimg = f_out + (size_t)bb*CHW;
  for (int e = tid; e < 8192; e += 256){
    int x = e & 15, y = (e>>4)&3, c = e>>6;
    size_t gi = (size_t)c*HW + (y0+y)*WW + x0 + x;
    float v = fimg[gi] - sa[y*16+x] * bf2f(fg[(y*16+x)*CP + c]);
    oimg[gi] = v;
  }
}

// ---------------------------------------------------------------------------
extern "C" void kernel_launch(void* const* d_in, const int* in_sizes, int n_in,
                              void* d_out, int out_size, void* d_ws, size_t ws_size,
                              hipStream_t stream) {
  const float* filter_map = (const float*)d_in[0];
  const float* ref        = (const float*)d_in[1];
  const float* label_w    = (const float*)d_in[2];
  const float* spatial_w  = (const float*)d_in[3];
  const float* mask_w     = (const float*)d_in[4];
  const float* lsl        = (const float*)d_in[5];
  const float* freg       = (const float*)d_in[6];

  // ws (~18.4 MB): coef 4 KB | fgrad bf16 16.78 MB | signs 1.57 MB
  char*  wsb   = (char*)d_ws;
  float* coef  = (float*)wsb;
  short* fgrad = (short*)(wsb + 4096);
  unsigned* signs = (unsigned*)(wsb + 4096 + (size_t)BB*CHW*sizeof(short));
  float* fbuf  = (float*)d_out;    // evolving filter lives in d_out (fp32)

  coef_kernel<<<dim3(1), dim3(128), 0, stream>>>(label_w, spatial_w, mask_w, lsl, freg, coef);

  dim3 grid(8, 32, BB);   // 16-col x-tiles, 4-row y-bands, batch
  for (int it = 0; it < 3; it++){
    const float* fsrc = (it == 0) ? filter_map : (const float*)fbuf;
    kA<<<grid, 256, 0, stream>>>(fsrc, ref, coef, fgrad, signs);
    kB<<<grid, 256, 0, stream>>>(fsrc, ref, fgrad, signs, coef, fbuf);
  }
}

// Round 6
// 750.635 us; speedup vs baseline: 3.4814x; 1.3659x over previous
//
#include <hip/hip_runtime.h>

#define BB 4
#define CC 128
#define HH 128
#define WW 128
#define HW (HH*WW)
#define CHW (CC*HW)
#define ND 81
#define CP 136      // c-stride (shorts) for uc/fgs: 272 B rows -> 16B aligned, 2-way-free b128 reads
#define UPITCH 40   // u-stride (shorts) for cu: 80 B rows, b64-write friendly
#define PP 32       // P tile u stride (shorts), 16B-aligned frag reads

typedef short s8v __attribute__((ext_vector_type(8)));   // 8 bf16 MFMA A/B frag
typedef short s4v __attribute__((ext_vector_type(4)));
typedef float f4v __attribute__((ext_vector_type(4)));   // MFMA C/D frag

__device__ __forceinline__ short f2bf(float x){          // RNE float->bf16 bits
  unsigned u = __float_as_uint(x);
  unsigned r = (u + 0x7FFFu + ((u >> 16) & 1u)) >> 16;
  return (short)r;
}
__device__ __forceinline__ float bf2f(short s){
  return __uint_as_float(((unsigned)(unsigned short)s) << 16);
}

// ---------------------------------------------------------------------------
// coef: [0..80]=target, [128..208]=vplus, [256..336]=alo, [384..464]=ahi,
//       [512]=step_length, [513]=reg_weight
// ---------------------------------------------------------------------------
__global__ void coef_kernel(const float* lw, const float* sw, const float* mw,
                            const float* lsl, const float* fr, float* coef){
  int d = threadIdx.x;
  if (d < ND){
    float dy = (float)(d / 9) - 4.0f;
    float dx = (float)(d % 9) - 4.0f;
    float dist = sqrtf(dy*dy + dx*dx) * 2.0f;
    float t = 0.f, v = 0.f, m = 0.f;
    for (int k = 0; k < 10; k++){
      float bd = dist - (float)k;
      float val = (k == 9) ? fminf(fmaxf(bd + 1.0f, 0.f), 1.f)
                           : fmaxf(1.0f - fabsf(bd), 0.f);
      t += val * lw[k]; v += val * sw[k]; m += val * mw[k];
    }
    float wm = 1.f / (1.f + expf(-m));
    coef[d] = t; coef[128+d] = v;
    coef[256+d] = (1.f - wm) * 0.5f;
    coef[384+d] = (1.f + wm) * 0.5f;
  }
  if (threadIdx.x == 0){
    coef[512] = expf(lsl[0]);
    float f = fr[0];
    coef[513] = fmaxf(f*f, 1e-10f) / (float)(CC*CC);
  }
}

// ---------------------------------------------------------------------------
// kF: fully fused iteration for one (bb, 4-row y-band, 16-col x-tile):
//  phase A: slide 12 ref rows; corr1 (MFMA, f hi/lo) -> mapped+signs -> P ->
//           corr_t MFMA accum D.  epilogue-1: fgs = bf16(D + rw*f); num.
//  phase B: slide 12 ref rows again; corr(fgrad) MFMA -> den atomics ->
//           alpha -> f_out = f - step*alpha*fgrad.
// LDS 29.2 KB: uc 8704 | fgs 17408 (phase-A overlay: cu 10240 + Pm 4096) |
//              coefs 1536 | sg 1536 | den/num/sa 768
// ---------------------------------------------------------------------------
#define L_UC   0
#define L_FGS  8704
#define L_CU   8704
#define L_PM   18944
#define L_CF   26112
#define L_SG   27648
#define L_DEN  29184
#define L_NUM  29440
#define L_SA   29696
#define L_SZ   29952

__global__ __launch_bounds__(256, 4)
void kF(const float* f_in, const float* ref, const float* coef, float* f_out){
  __shared__ char smem[L_SZ];
  short* uc  = (short*)(smem + L_UC);    // [32 u][CP c]   (corr B-operand)
  short* cu  = (short*)(smem + L_CU);    // [128 c][UPITCH u] (corr_t B-operand, phase A)
  short* Pm  = (short*)(smem + L_PM);    // [4 wv][16 x][PP u]
  short* fgs = (short*)(smem + L_FGS);   // [64 px][CP c]  (fgrad, after phase A)
  float* s_t = (float*)(smem + L_CF);
  float* s_v = s_t + 96; float* s_al = s_t + 192; float* s_ah = s_t + 288;
  unsigned* sg = (unsigned*)(smem + L_SG);
  float* den = (float*)(smem + L_DEN);
  float* num = (float*)(smem + L_NUM);
  float* sa  = (float*)(smem + L_SA);

  int tid = threadIdx.x;
  int lane = tid & 63, wv = tid >> 6;
  int quad = lane >> 4, col = lane & 15;
  int bb = blockIdx.z, y0 = blockIdx.y * 4, x0 = blockIdx.x * 16;
  int ub = x0 - 8;
  bool interior = (ub >= 0) && (ub + 32 <= WW);

  const float* fimg = f_in + (size_t)bb * CHW;
  const float* rimg = ref  + (size_t)bb * CHW;

  if (tid < ND){
    s_t[tid]  = coef[tid];       s_v[tid]  = coef[128+tid];
    s_al[tid] = coef[256+tid];   s_ah[tid] = coef[384+tid];
  }
  for (int e = tid; e < 384; e += 256) sg[e] = 0;
  if (tid < 64) den[tid] = 0.f;

  // ---- A-frags (f at row y0+wv, hi/lo split) straight from global ----
  int fy = y0 + wv;
  s8v a_hi[4], a_lo[4];
  #pragma unroll
  for (int kc = 0; kc < 4; kc++){
    short th[8], tl[8];
    #pragma unroll
    for (int j = 0; j < 8; j++){
      int c = kc*32 + quad*8 + j;
      float v = fimg[(size_t)c * HW + fy * WW + x0 + col];
      short h = f2bf(v);
      th[j] = h; tl[j] = f2bf(v - bf2f(h));
    }
    a_hi[kc] = *(const s8v*)th;
    a_lo[kc] = *(const s8v*)tl;
  }

  f4v D[8];
  #pragma unroll
  for (int i = 0; i < 8; i++) D[i] = (f4v)0.f;

  // =================== phase A: corr1 -> P -> corr_t ===================
  for (int rr = 0; rr < 12; rr++){
    int r = y0 + rr - 4;
    __syncthreads();
    if (r >= 0 && r < HH){
      if (interior){
        #pragma unroll
        for (int k = 0; k < 4; k++){
          int e4 = tid + k*256;
          int u4 = (e4 & 7) * 4, c = e4 >> 3;
          float4 v = *(const float4*)(rimg + (size_t)c*HW + r*WW + ub + u4);
          short h0=f2bf(v.x), h1=f2bf(v.y), h2=f2bf(v.z), h3=f2bf(v.w);
          uc[(u4+0)*CP + c] = h0; uc[(u4+1)*CP + c] = h1;
          uc[(u4+2)*CP + c] = h2; uc[(u4+3)*CP + c] = h3;
          s4v pk = {h0, h1, h2, h3};
          *(s4v*)&cu[c*UPITCH + u4] = pk;
        }
      } else {
        for (int e = tid; e < 4096; e += 256){
          int u = e & 31, c = e >> 5;
          int ua = ub + u;
          float v = (ua >= 0 && ua < WW) ? rimg[(size_t)c*HW + r*WW + ua] : 0.f;
          short h = f2bf(v);
          uc[u*CP + c] = h;
          cu[c*UPITCH + u] = h;
        }
      }
    }
    __syncthreads();
    int dy = rr - wv;
    if (r >= 0 && r < HH && dy >= 0 && dy <= 8){
      // corr1: C[x,u] = sum_c (f_hi+f_lo)[x,c] * ref[c,u]
      f4v C0 = (f4v)0.f, C1 = (f4v)0.f;
      #pragma unroll
      for (int kc = 0; kc < 4; kc++){
        s8v b0 = *(const s8v*)&uc[col*CP      + kc*32 + quad*8];
        s8v b1 = *(const s8v*)&uc[(16+col)*CP + kc*32 + quad*8];
        C0 = __builtin_amdgcn_mfma_f32_16x16x32_bf16(a_hi[kc], b0, C0, 0,0,0);
        C0 = __builtin_amdgcn_mfma_f32_16x16x32_bf16(a_lo[kc], b0, C0, 0,0,0);
        C1 = __builtin_amdgcn_mfma_f32_16x16x32_bf16(a_hi[kc], b1, C1, 0,0,0);
        C1 = __builtin_amdgcn_mfma_f32_16x16x32_bf16(a_lo[kc], b1, C1, 0,0,0);
      }
      // scores -> signs + mapped -> P[x,u]
      #pragma unroll
      for (int nt = 0; nt < 2; nt++){
        f4v Cv = nt ? C1 : C0;
        #pragma unroll
        for (int reg = 0; reg < 4; reg++){
          int x  = quad*4 + reg;            // C/D row = (lane>>4)*4 + reg
          int up = nt*16 + col;             // C/D col = lane&15 (+tile)
          int dxm = up - x - 4;
          float m = 0.f;
          if (dxm >= 0 && dxm <= 8){
            float s = Cv[reg];
            int d = dy*9 + dxm;
            int px = wv*16 + x;
            float sgn = 0.f;
            if (s > 0.f){ sgn =  1.f; atomicOr(&sg[px*6     + (d>>5)], 1u << (d & 31)); }
            if (s < 0.f){ sgn = -1.f; atomicOr(&sg[px*6 + 3 + (d>>5)], 1u << (d & 31)); }
            float vp = s_v[d], al = s_al[d], ah = s_ah[d];
            float ga  = vp * (al * sgn + ah);
            float act = vp * (al * fabsf(s) + ah * s);
            m = ga * (act - vp * s_t[d]);
          }
          Pm[(wv*16 + x)*PP + up] = f2bf(m);
        }
      }
      __builtin_amdgcn_s_waitcnt(0);        // wave-local LDS handoff
      // corr_t: D[x,c] += sum_u P[x,u] * ref[u,c]
      s8v pa = *(const s8v*)&Pm[(wv*16 + col)*PP + quad*8];
      #pragma unroll
      for (int ct = 0; ct < 8; ct++){
        s8v bc = *(const s8v*)&cu[(ct*16 + col)*UPITCH + quad*8];
        D[ct] = __builtin_amdgcn_mfma_f32_16x16x32_bf16(pa, bc, D[ct], 0,0,0);
      }
    }
  }

  // ---- epilogue-1: fgs = bf16(D + rw*f) (overlays cu+Pm), then num ----
  float rw = coef[513];
  __syncthreads();
  #pragma unroll
  for (int ct = 0; ct < 8; ct++){
    #pragma unroll
    for (int reg = 0; reg < 4; reg++){
      int x = quad*4 + reg, c = ct*16 + col;
      float fv = fimg[(size_t)c * HW + fy * WW + x0 + x];
      fgs[(wv*16 + x)*CP + c] = f2bf(D[ct][reg] + rw * fv);
    }
  }
  __syncthreads();
  if (tid < 64){
    float s = 0.f;
    #pragma unroll
    for (int kc = 0; kc < 16; kc++){
      s8v v = *(const s8v*)&fgs[tid*CP + kc*8];
      #pragma unroll
      for (int j = 0; j < 8; j++){ float f = bf2f(v[j]); s += f*f; }
    }
    num[tid] = s;
  }

  // =================== phase B: corr(fgrad) -> den -> update ===================
  s8v ga_[4];
  #pragma unroll
  for (int kc = 0; kc < 4; kc++)
    ga_[kc] = *(const s8v*)&fgs[(wv*16 + col)*CP + kc*32 + quad*8];

  for (int rr = 0; rr < 12; rr++){
    int r = y0 + rr - 4;
    __syncthreads();
    if (r >= 0 && r < HH){
      if (interior){
        #pragma unroll
        for (int k = 0; k < 4; k++){
          int e4 = tid + k*256;
          int u4 = (e4 & 7) * 4, c = e4 >> 3;
          float4 v = *(const float4*)(rimg + (size_t)c*HW + r*WW + ub + u4);
          uc[(u4+0)*CP + c] = f2bf(v.x); uc[(u4+1)*CP + c] = f2bf(v.y);
          uc[(u4+2)*CP + c] = f2bf(v.z); uc[(u4+3)*CP + c] = f2bf(v.w);
        }
      } else {
        for (int e = tid; e < 4096; e += 256){
          int u = e & 31, c = e >> 5;
          int ua = ub + u;
          float v = (ua >= 0 && ua < WW) ? rimg[(size_t)c*HW + r*WW + ua] : 0.f;
          uc[u*CP + c] = f2bf(v);
        }
      }
    }
    __syncthreads();
    int dy = rr - wv;
    if (r >= 0 && r < HH && dy >= 0 && dy <= 8){
      f4v C0 = (f4v)0.f, C1 = (f4v)0.f;
      #pragma unroll
      for (int kc = 0; kc < 4; kc++){
        s8v b0 = *(const s8v*)&uc[col*CP      + kc*32 + quad*8];
        s8v b1 = *(const s8v*)&uc[(16+col)*CP + kc*32 + quad*8];
        C0 = __builtin_amdgcn_mfma_f32_16x16x32_bf16(ga_[kc], b0, C0, 0,0,0);
        C1 = __builtin_amdgcn_mfma_f32_16x16x32_bf16(ga_[kc], b1, C1, 0,0,0);
      }
      #pragma unroll
      for (int nt = 0; nt < 2; nt++){
        f4v Cv = nt ? C1 : C0;
        #pragma unroll
        for (int reg = 0; reg < 4; reg++){
          int x  = quad*4 + reg;
          int up = nt*16 + col;
          int dxm = up - x - 4;
          if (dxm >= 0 && dxm <= 8){
            int d = dy*9 + dxm;
            int px = wv*16 + x;
            float sgn = ((sg[px*6 + (d>>5)] >> (d&31)) & 1u) ? 1.f
                      : (((sg[px*6 + 3 + (d>>5)] >> (d&31)) & 1u) ? -1.f : 0.f);
            float ga = s_v[d] * (s_al[d]*sgn + s_ah[d]);
            float t  = Cv[reg];
            float sgv = ga * t;
            atomicAdd(&den[px], sgv*sgv);
          }
        }
      }
    }
  }

  __syncthreads();
  if (tid < 64){
    float step = coef[512];
    float alpha = num[tid] / fmaxf(den[tid] + rw*num[tid], 1e-8f);
    sa[tid] = step * alpha;
  }
  __syncthreads();

  // ---- update: f_out = f - step*alpha*fgrad (coalesced) ----
  float* oimg = f_out + (size_t)bb * CHW;
  for (int e = tid; e < 8192; e += 256){
    int x = e & 15, y = (e >> 4) & 3, c = e >> 6;
    size_t gi = (size_t)c * HW + (y0 + y) * WW + x0 + x;
    float v = fimg[gi] - sa[y*16 + x] * bf2f(fgs[(y*16 + x)*CP + c]);
    oimg[gi] = v;
  }
}

// ---------------------------------------------------------------------------
extern "C" void kernel_launch(void* const* d_in, const int* in_sizes, int n_in,
                              void* d_out, int out_size, void* d_ws, size_t ws_size,
                              hipStream_t stream) {
  const float* filter_map = (const float*)d_in[0];
  const float* ref        = (const float*)d_in[1];
  const float* label_w    = (const float*)d_in[2];
  const float* spatial_w  = (const float*)d_in[3];
  const float* mask_w     = (const float*)d_in[4];
  const float* lsl        = (const float*)d_in[5];
  const float* freg       = (const float*)d_in[6];

  float* coef = (float*)d_ws;      // 1024 floats
  float* fbuf = (float*)d_out;     // evolving filter lives in d_out (fp32)

  coef_kernel<<<dim3(1), dim3(128), 0, stream>>>(label_w, spatial_w, mask_w, lsl, freg, coef);

  dim3 grid(8, 32, BB);   // 16-col x-tiles, 4-row y-bands, batch
  for (int it = 0; it < 3; it++){
    const float* fsrc = (it == 0) ? filter_map : (const float*)fbuf;
    kF<<<grid, 256, 0, stream>>>(fsrc, ref, coef, fbuf);
  }
}